// Round 10
// baseline (368.468 us; speedup 1.0000x reference)
//
#include <hip/hip_runtime.h>
#include <hip/hip_cooperative_groups.h>
#include <math.h>

namespace cg = cooperative_groups;

// Preisach hysteresis, single cooperative kernel (3 phases, 2 grid syncs).
// Round-9's 3-kernel pipeline measured 24.9us with ~9us of kernel work --
// the rest was graph-node launch/serialization overhead. Phases:
//  P0: stage h-slice to LDS; row prefix scans -> Cg (wave per row, one
//      6-step shfl chain); per-block chunk stats computed locally from LDS.
//  P1: column prefix scans on Cg (wave per column).
//  P2: wave-per-t exact backward-record scan (validated rounds 7/9 math).
//
// Table: C[a][b] = sum_{alpha_idx<a, beta_idx<b, beta<=alpha} softplus(raw),
// a,b in [0,L], row-major stride SP=202. packed p(i,j)=L*i-i(i-1)/2+(j-i).

__device__ __forceinline__ float softplus_f(float x) {
    return fmaxf(x, 0.0f) + log1pf(expf(-fabsf(x)));
}

__global__ __launch_bounds__(256) void hyst_coop(
    const float* __restrict__ h,
    const float* __restrict__ mesh,
    const float* __restrict__ raw,
    const float* __restrict__ scale,
    const float* __restrict__ offset,
    float* __restrict__ out,
    float* __restrict__ Cg,
    int T, int L, int n)
{
    extern __shared__ float sm[];
    const int W  = L + 1;
    const int SP = (W + 1) & ~1;
    const int nc = (T + 63) >> 6;

    float* lh  = sm;         // T floats (block stages only its prefix)
    float* us  = sm + T;     // nc
    float* dsm = us + nc;    // nc

    const int tid  = threadIdx.x;
    const int lane = tid & 63;
    const int wid  = tid >> 6;
    const int nwv  = blockDim.x >> 6;          // 4
    const int bid  = blockIdx.x;
    const int gw   = bid * nwv + wid;          // global wave id

    cg::grid_group grid = cg::this_grid();

    // ---- P0a: stage h[0..tmax] into LDS (float4) ----
    const int tmax = min(T - 1, (bid + 1) * nwv - 1);
    const int nh4  = (tmax + 4) >> 2;
    const float4* h4 = (const float4*)h;
    float4* lh4 = (float4*)lh;
    for (int k = tid; k < nh4; k += blockDim.x) lh4[k] = h4[k];

    // ---- P0b: row prefix into Cg (global wave j per row) ----
    if (gw < L) {
        const int j = gw;
        float* row = Cg + (size_t)(j + 1) * SP;
        float s[4];
        float run = 0.0f;
#pragma unroll
        for (int q = 0; q < 4; ++q) {
            const int i = 4 * lane + q;          // beta index
            float d = 0.0f;
            if (i <= j) {
                const int p = L * i - (i * (i - 1)) / 2 + (j - i);
                d = softplus_f(raw[p]);
            }
            run += d; s[q] = run;                // lane-local inclusive
        }
        float x = run;
        for (int o = 1; o < 64; o <<= 1) {
            const float tv = __shfl_up(x, o);
            if (lane >= o) x += tv;
        }
        const float excl = x - run;
#pragma unroll
        for (int q = 0; q < 4; ++q) {
            const int i = 4 * lane + q;
            if (i <= j) row[i + 1] = excl + s[q];
        }
        const float total = __shfl(x, 63);
        for (int b = j + 2 + lane; b <= L; b += 64) row[b] = total;
        if (lane == 0) row[0] = 0.0f;
        if (j == 0) {
            for (int b = lane; b <= L; b += 64) Cg[b] = 0.0f;  // row a=0
        }
    }

    __syncthreads();   // lh staged

    // ---- P0c: per-block chunk stats from LDS (full chunks below top) ----
    const int ncf = tmax >> 6;     // stats needed only for c < own ct <= ncf
    for (int c = wid; c < ncf; c += nwv) {
        const int i = (c << 6) + lane;           // i <= ncf*64-1 <= tmax
        const float hv = lh[i];
        const float hp = (i > 0) ? lh[i - 1] : 0.0f;
        float mu = (hv > hp) ? hv : -1.0f;
        float md = (hv < hp) ? hv : 2.0f;
        for (int o = 1; o < 64; o <<= 1) {
            mu = fmaxf(mu, __shfl_xor(mu, o));
            md = fminf(md, __shfl_xor(md, o));
        }
        if (lane == 0) { us[c] = mu; dsm[c] = md; }
    }

    // xs levels: lane holds levels lane, +64, +128, +192
    float xsr[4];
#pragma unroll
    for (int k = 0; k < 4; ++k) {
        const int jj = lane + 64 * k;
        xsr[k] = (jj < L) ? mesh[2 * jj + 1] : 2.0f;  // 2.0 never matches
    }

    __threadfence();
    grid.sync();       // row prefixes visible grid-wide

    // ---- P1: column prefix on Cg (global wave b per column) ----
    if (gw < W) {
        const int b = gw;
        float v[4];
        float run = 0.0f;
#pragma unroll
        for (int q = 0; q < 4; ++q) {
            const int a = 1 + 4 * lane + q;
            const float d = (a <= L) ? Cg[(size_t)a * SP + b] : 0.0f;
            run += d; v[q] = run;
        }
        float x = run;
        for (int o = 1; o < 64; o <<= 1) {
            const float tv = __shfl_up(x, o);
            if (lane >= o) x += tv;
        }
        const float excl = x - run;
#pragma unroll
        for (int q = 0; q < 4; ++q) {
            const int a = 1 + 4 * lane + q;
            if (a <= L) Cg[(size_t)a * SP + b] = excl + v[q];
        }
    }

    __threadfence();
    grid.sync();       // full table visible grid-wide

    // ---- P2: main, one wave per t ----
    const int t = gw;
    if (t >= T) return;

    float u_max = -1.0f, d_min = 2.0f;
    int Acov = 0, Bcov = L;
    int nrec = 0;                 // wave-uniform
    int r_up = 0, r_lo = 0, r_Ap = 0, r_Bp = 0;   // per-lane record slot
    float acc = 0.0f;             // per-lane deferred contributions

    auto flushrec = [&]() {
        if (lane < nrec) {
            float contrib;
            if (r_up) {
                contrib = Cg[r_lo * SP + r_Bp] - Cg[r_Ap * SP + r_Bp];
            } else {
                contrib = -((Cg[L * SP + r_Bp] - Cg[L * SP + r_lo])
                          - (Cg[r_Ap * SP + r_Bp] - Cg[r_Ap * SP + r_lo]));
            }
            acc += contrib;
        }
        nrec = 0;
    };
    auto count_le = [&](float v) -> int {
        return __popcll(__ballot(xsr[0] <= v)) + __popcll(__ballot(xsr[1] <= v))
             + __popcll(__ballot(xsr[2] <= v)) + __popcll(__ballot(xsr[3] <= v));
    };
    auto count_lt = [&](float v) -> int {
        return __popcll(__ballot(xsr[0] < v)) + __popcll(__ballot(xsr[1] < v))
             + __popcll(__ballot(xsr[2] < v)) + __popcll(__ballot(xsr[3] < v));
    };
    auto process_chunk = [&](int c) {
        const int i = (c << 6) + lane;
        const float hv = lh[i];
        const float hp = (i > 0) ? lh[i - 1] : 0.0f;
        const bool valid = (i <= t);
        const bool isup = valid && (hv > hp);
        const bool isdn = valid && (hv < hp);
        unsigned long long mup = __ballot(isup && hv > u_max);
        unsigned long long mdn = __ballot(isdn && hv < d_min);
        unsigned long long m = mup | mdn;
        while (m) {
            const int rl = 63 - __builtin_clzll(m);   // largest i first
            const float v = __shfl(hv, rl);
            if ((mup >> rl) & 1ull) {
                u_max = v;
                const int lo = count_le(v);
                if (lo > Acov) {
                    if (lane == nrec) { r_up = 1; r_lo = lo; r_Ap = Acov; r_Bp = Bcov; }
                    ++nrec;
                    Acov = lo;
                    if (nrec == 64) flushrec();
                }
            } else {
                d_min = v;
                const int lo = count_lt(v);
                if (lo < Bcov) {
                    if (lane == nrec) { r_up = 0; r_lo = lo; r_Ap = Acov; r_Bp = Bcov; }
                    ++nrec;
                    Bcov = lo;
                    if (nrec == 64) flushrec();
                }
            }
            const unsigned long long below =
                (rl == 0) ? 0ull : ((1ull << rl) - 1ull);
            mup = __ballot(isup && hv > u_max) & below;
            mdn = __ballot(isdn && hv < d_min) & below;
            m = mup | mdn;
        }
    };

    const int ct = t >> 6;
    process_chunk(ct);  // partial top chunk (valid mask), exact

    for (int g = (ct - 1) >> 6; g >= 0; --g) {   // ct==0 -> skipped
        if (Acov >= L || Bcov <= 0) break;
        const int cbase = g << 6;
        const int c = cbase + lane;
        const bool act = (c < ct);
        const float vu = act ? us[c] : -1.0f;
        const float vd = act ? dsm[c] : 2.0f;
        // suffix scans (higher lanes = later chunks in backward order)
        float su = vu, sd = vd;
        for (int o = 1; o < 64; o <<= 1) {
            su = fmaxf(su, __shfl_down(su, o));
            sd = fminf(sd, __shfl_down(sd, o));
        }
        float sue = __shfl_down(su, 1);
        float sde = __shfl_down(sd, 1);
        if (lane == 63) { sue = -1.0f; sde = 2.0f; }
        const bool enter = act && ((vu > fmaxf(u_max, sue)) ||
                                   (vd < fminf(d_min, sde)));
        unsigned long long em = __ballot(enter);
        while (em) {
            const int rl = 63 - __builtin_clzll(em);
            process_chunk(cbase + rl);
            em &= ~(1ull << rl);
            if (Acov >= L || Bcov <= 0) break;
        }
    }

    flushrec();
    // leftover region keeps initial -1
    if (lane == 0) acc -= Cg[L * SP + Bcov] - Cg[Acov * SP + Bcov];
    for (int o = 1; o < 64; o <<= 1) acc += __shfl_xor(acc, o);
    if (lane == 0) out[t] = scale[0] * (acc / (float)n) + offset[0];
}

// ---------------- fallback path (round-9 3-kernel pipeline) ----------------

__global__ __launch_bounds__(256) void build_rows_stats(
    const float* __restrict__ h, const float* __restrict__ raw,
    float* __restrict__ Cg, float* __restrict__ statg,
    int T, int L, int nrowblocks)
{
    const int W  = L + 1;
    const int SP = (W + 1) & ~1;
    const int nc = (T + 63) >> 6;
    const int lane = threadIdx.x & 63;
    const int wid  = threadIdx.x >> 6;
    const int nwv  = blockDim.x >> 6;

    if ((int)blockIdx.x < nrowblocks) {
        const int j = blockIdx.x * nwv + wid;
        if (j >= L) return;
        float* row = Cg + (size_t)(j + 1) * SP;
        float s[4];
        float run = 0.0f;
#pragma unroll
        for (int q = 0; q < 4; ++q) {
            const int i = 4 * lane + q;
            float d = 0.0f;
            if (i <= j) {
                const int p = L * i - (i * (i - 1)) / 2 + (j - i);
                d = softplus_f(raw[p]);
            }
            run += d; s[q] = run;
        }
        float x = run;
        for (int o = 1; o < 64; o <<= 1) {
            const float tv = __shfl_up(x, o);
            if (lane >= o) x += tv;
        }
        const float excl = x - run;
#pragma unroll
        for (int q = 0; q < 4; ++q) {
            const int i = 4 * lane + q;
            if (i <= j) row[i + 1] = excl + s[q];
        }
        const float total = __shfl(x, 63);
        for (int b = j + 2 + lane; b <= L; b += 64) row[b] = total;
        if (lane == 0) row[0] = 0.0f;
        if (j == 0) {
            for (int b = lane; b <= L; b += 64) Cg[b] = 0.0f;
        }
    } else {
        const int c = ((int)blockIdx.x - nrowblocks) * nwv + wid;
        if (c >= nc) return;
        const int i = (c << 6) + lane;
        const bool inb = (i < T);
        const float hv = inb ? h[i] : 0.0f;
        const float hp = (inb && i > 0) ? h[i - 1] : 0.0f;
        float mu = (inb && hv > hp) ? hv : -1.0f;
        float md = (inb && hv < hp) ? hv : 2.0f;
        for (int o = 1; o < 64; o <<= 1) {
            mu = fmaxf(mu, __shfl_xor(mu, o));
            md = fminf(md, __shfl_xor(md, o));
        }
        if (lane == 0) { statg[c] = mu; statg[nc + c] = md; }
    }
}

__global__ __launch_bounds__(256) void build_cols(float* __restrict__ Cg, int L)
{
    const int W  = L + 1;
    const int SP = (W + 1) & ~1;
    const int lane = threadIdx.x & 63;
    const int b = blockIdx.x * (blockDim.x >> 6) + (threadIdx.x >> 6);
    if (b >= W) return;
    float v[4];
    float run = 0.0f;
#pragma unroll
    for (int q = 0; q < 4; ++q) {
        const int a = 1 + 4 * lane + q;
        const float d = (a <= L) ? Cg[(size_t)a * SP + b] : 0.0f;
        run += d; v[q] = run;
    }
    float x = run;
    for (int o = 1; o < 64; o <<= 1) {
        const float tv = __shfl_up(x, o);
        if (lane >= o) x += tv;
    }
    const float excl = x - run;
#pragma unroll
    for (int q = 0; q < 4; ++q) {
        const int a = 1 + 4 * lane + q;
        if (a <= L) Cg[(size_t)a * SP + b] = excl + v[q];
    }
}

__global__ __launch_bounds__(256) void hyst_main(
    const float* __restrict__ h, const float* __restrict__ mesh,
    const float* __restrict__ Cg, const float* __restrict__ statg,
    const float* __restrict__ scale, const float* __restrict__ offset,
    float* __restrict__ out, int T, int L, int n)
{
    extern __shared__ float sm[];
    const int W  = L + 1;
    const int SP = (W + 1) & ~1;
    const int nc = (T + 63) >> 6;
    float* lh = sm;
    float* us = sm + T;
    float* dsm = us + nc;

    const int tid  = threadIdx.x;
    const int lane = tid & 63;
    const int wid  = tid >> 6;
    const int nwv  = blockDim.x >> 6;

    const int tmax = min(T - 1, (int)(blockIdx.x + 1) * nwv - 1);
    const int nh4  = (tmax + 4) >> 2;
    const float4* h4 = (const float4*)h;
    float4* lh4 = (float4*)lh;
    for (int k = tid; k < nh4; k += blockDim.x) lh4[k] = h4[k];
    const int ncb = (tmax >> 6) + 1;
    for (int k = tid; k < ncb; k += blockDim.x) {
        us[k] = statg[k]; dsm[k] = statg[nc + k];
    }

    float xsr[4];
#pragma unroll
    for (int k = 0; k < 4; ++k) {
        const int jj = lane + 64 * k;
        xsr[k] = (jj < L) ? mesh[2 * jj + 1] : 2.0f;
    }
    __syncthreads();

    const int t = blockIdx.x * nwv + wid;
    if (t >= T) return;

    float u_max = -1.0f, d_min = 2.0f;
    int Acov = 0, Bcov = L;
    int nrec = 0;
    int r_up = 0, r_lo = 0, r_Ap = 0, r_Bp = 0;
    float acc = 0.0f;

    auto flushrec = [&]() {
        if (lane < nrec) {
            float contrib;
            if (r_up) {
                contrib = Cg[r_lo * SP + r_Bp] - Cg[r_Ap * SP + r_Bp];
            } else {
                contrib = -((Cg[L * SP + r_Bp] - Cg[L * SP + r_lo])
                          - (Cg[r_Ap * SP + r_Bp] - Cg[r_Ap * SP + r_lo]));
            }
            acc += contrib;
        }
        nrec = 0;
    };
    auto count_le = [&](float v) -> int {
        return __popcll(__ballot(xsr[0] <= v)) + __popcll(__ballot(xsr[1] <= v))
             + __popcll(__ballot(xsr[2] <= v)) + __popcll(__ballot(xsr[3] <= v));
    };
    auto count_lt = [&](float v) -> int {
        return __popcll(__ballot(xsr[0] < v)) + __popcll(__ballot(xsr[1] < v))
             + __popcll(__ballot(xsr[2] < v)) + __popcll(__ballot(xsr[3] < v));
    };
    auto process_chunk = [&](int c) {
        const int i = (c << 6) + lane;
        const float hv = lh[i];
        const float hp = (i > 0) ? lh[i - 1] : 0.0f;
        const bool valid = (i <= t);
        const bool isup = valid && (hv > hp);
        const bool isdn = valid && (hv < hp);
        unsigned long long mup = __ballot(isup && hv > u_max);
        unsigned long long mdn = __ballot(isdn && hv < d_min);
        unsigned long long m = mup | mdn;
        while (m) {
            const int rl = 63 - __builtin_clzll(m);
            const float v = __shfl(hv, rl);
            if ((mup >> rl) & 1ull) {
                u_max = v;
                const int lo = count_le(v);
                if (lo > Acov) {
                    if (lane == nrec) { r_up = 1; r_lo = lo; r_Ap = Acov; r_Bp = Bcov; }
                    ++nrec;
                    Acov = lo;
                    if (nrec == 64) flushrec();
                }
            } else {
                d_min = v;
                const int lo = count_lt(v);
                if (lo < Bcov) {
                    if (lane == nrec) { r_up = 0; r_lo = lo; r_Ap = Acov; r_Bp = Bcov; }
                    ++nrec;
                    Bcov = lo;
                    if (nrec == 64) flushrec();
                }
            }
            const unsigned long long below =
                (rl == 0) ? 0ull : ((1ull << rl) - 1ull);
            mup = __ballot(isup && hv > u_max) & below;
            mdn = __ballot(isdn && hv < d_min) & below;
            m = mup | mdn;
        }
    };

    const int ct = t >> 6;
    process_chunk(ct);

    for (int g = (ct - 1) >> 6; g >= 0; --g) {
        if (Acov >= L || Bcov <= 0) break;
        const int cbase = g << 6;
        const int c = cbase + lane;
        const bool act = (c < ct);
        const float vu = act ? us[c] : -1.0f;
        const float vd = act ? dsm[c] : 2.0f;
        float su = vu, sd = vd;
        for (int o = 1; o < 64; o <<= 1) {
            su = fmaxf(su, __shfl_down(su, o));
            sd = fminf(sd, __shfl_down(sd, o));
        }
        float sue = __shfl_down(su, 1);
        float sde = __shfl_down(sd, 1);
        if (lane == 63) { sue = -1.0f; sde = 2.0f; }
        const bool enter = act && ((vu > fmaxf(u_max, sue)) ||
                                   (vd < fminf(d_min, sde)));
        unsigned long long em = __ballot(enter);
        while (em) {
            const int rl = 63 - __builtin_clzll(em);
            process_chunk(cbase + rl);
            em &= ~(1ull << rl);
            if (Acov >= L || Bcov <= 0) break;
        }
    }

    flushrec();
    if (lane == 0) acc -= Cg[L * SP + Bcov] - Cg[Acov * SP + Bcov];
    for (int o = 1; o < 64; o <<= 1) acc += __shfl_xor(acc, o);
    if (lane == 0) out[t] = scale[0] * (acc / (float)n) + offset[0];
}

extern "C" void kernel_launch(void* const* d_in, const int* in_sizes, int n_in,
                              void* d_out, int out_size, void* d_ws, size_t ws_size,
                              hipStream_t stream) {
    const float* h      = (const float*)d_in[0];
    const float* mesh   = (const float*)d_in[1];
    const float* raw    = (const float*)d_in[2];
    const float* scale  = (const float*)d_in[3];
    const float* offset = (const float*)d_in[4];
    float* out = (float*)d_out;

    const int T = in_sizes[0];
    const int n = in_sizes[2];
    const int L = (int)((sqrt(8.0 * (double)n + 1.0) - 1.0) / 2.0 + 0.5);
    const int W = L + 1;
    const int SP = (W + 1) & ~1;
    const int nc = (T + 63) / 64;

    float* Cg    = (float*)d_ws;              // W*SP floats
    float* statg = Cg + (size_t)W * SP;       // 2*nc floats (fallback only)

    const int nwv = 4;                         // 256 threads = 4 waves
    const int grid = (T + nwv - 1) / nwv;      // 1024 blocks (4/CU)
    const size_t shmem = (size_t)(T + 2 * nc) * sizeof(float);  // ~16.9 KB

    void* args[] = { (void*)&h, (void*)&mesh, (void*)&raw, (void*)&scale,
                     (void*)&offset, (void*)&out, (void*)&Cg,
                     (void*)&T, (void*)&L, (void*)&n };
    hipError_t err = hipLaunchCooperativeKernel(
        reinterpret_cast<const void*>(hyst_coop), dim3(grid), dim3(256),
        args, (unsigned int)shmem, stream);

    if (err != hipSuccess) {
        // deterministic fallback: round-9 3-kernel pipeline
        const int nrowblocks  = (L + 3) / 4;
        const int nstatblocks = (nc + 3) / 4;
        hipLaunchKernelGGL(build_rows_stats, dim3(nrowblocks + nstatblocks),
                           dim3(256), 0, stream, h, raw, Cg, statg, T, L,
                           nrowblocks);
        const int ncolblocks = (W + 3) / 4;
        hipLaunchKernelGGL(build_cols, dim3(ncolblocks), dim3(256), 0, stream,
                           Cg, L);
        hipLaunchKernelGGL(hyst_main, dim3(grid), dim3(256), shmem, stream,
                           h, mesh, Cg, statg, scale, offset, out, T, L, n);
    }
}

// Round 11
// 73.619 us; speedup vs baseline: 5.0051x; 5.0051x over previous
//
#include <hip/hip_runtime.h>
#include <math.h>

// Preisach hysteresis, TWO kernels (round-9's 3-kernel pipeline measured
// 24.9us with ~9us of work; cooperative grid.sync measured ~170us/sync in
// round 10 -- never again for us-scale kernels):
//  K1 build_all (ONE block x 1024 thr): whole 2D prefix table built in LDS
//     (row phase = round-9 single-shfl-chain scans; col phase = serial-over-a
//     register accumulation on float2 column pairs, conflict-free and
//     pipelined -- no register arrays, no carry chains, so no spills),
//     then written once to global Cg. Also per-64-chunk up-max/down-min
//     stats. Removes one graph node vs round 9.
//  K2 hyst_main: byte-identical to validated round-9 kernel.
//
// Table: C[a][b] = sum_{alpha_idx<a, beta_idx<b, beta<=alpha} softplus(raw),
// a,b in [0,L], row-major stride SP=202. packed p(i,j)=L*i-i(i-1)/2+(j-i).
// Single-chain row scans assume L+1 <= 256 (here L=200).

__device__ __forceinline__ float softplus_f(float x) {
    return fmaxf(x, 0.0f) + log1pf(expf(-fabsf(x)));
}

__global__ __launch_bounds__(1024) void build_all(
    const float* __restrict__ h,
    const float* __restrict__ raw,
    float* __restrict__ Cg,      // W*SP floats
    float* __restrict__ statg,   // 2*nc floats
    int T, int L)
{
    extern __shared__ float S[];
    const int W  = L + 1;            // 201
    const int SP = (W + 1) & ~1;     // 202
    const int nc = (T + 63) >> 6;

    const int tid  = threadIdx.x;
    const int lane = tid & 63;
    const int wid  = tid >> 6;            // 0..15
    const int nwv  = blockDim.x >> 6;     // 16

    // ---- per-chunk up-move max / down-move min (global h, wave/chunk) ----
    for (int c = wid; c < nc; c += nwv) {
        const int i = (c << 6) + lane;
        const bool inb = (i < T);
        const float hv = inb ? h[i] : 0.0f;
        const float hp = (inb && i > 0) ? h[i - 1] : 0.0f;
        float mu = (inb && hv > hp) ? hv : -1.0f;
        float md = (inb && hv < hp) ? hv : 2.0f;
        for (int o = 1; o < 64; o <<= 1) {
            mu = fmaxf(mu, __shfl_xor(mu, o));
            md = fminf(md, __shfl_xor(md, o));
        }
        if (lane == 0) { statg[c] = mu; statg[nc + c] = md; }
    }

    // ---- row prefix into LDS: wave per row j; lane owns i = 4l..4l+3 ----
    for (int j = wid; j < L; j += nwv) {
        float* row = S + (j + 1) * SP;
        float s[4];
        float run = 0.0f;
#pragma unroll
        for (int q = 0; q < 4; ++q) {
            const int i = 4 * lane + q;          // beta index
            float d = 0.0f;
            if (i <= j) {
                const int p = L * i - (i * (i - 1)) / 2 + (j - i);
                d = softplus_f(raw[p]);
            }
            run += d; s[q] = run;                // lane-local inclusive
        }
        float x = run;                           // lane total
        for (int o = 1; o < 64; o <<= 1) {
            const float tv = __shfl_up(x, o);
            if (lane >= o) x += tv;
        }
        const float excl = x - run;              // exclusive prefix of lanes
#pragma unroll
        for (int q = 0; q < 4; ++q) {
            const int i = 4 * lane + q;
            if (i <= j) row[i + 1] = excl + s[q];
        }
        const float total = __shfl(x, 63);
        for (int b = j + 2 + lane; b <= L; b += 64) row[b] = total;
        if (lane == 0) row[0] = 0.0f;
    }
    if (wid == 0) {
        for (int b = lane; b <= L; b += 64) S[b] = 0.0f;  // row a=0
    }
    __syncthreads();

    // ---- col accumulate: 2 waves own float2 column-pairs; serial over a
    //      with register running sums (row-contiguous LDS: conflict-free) ----
    if (wid < 2) {
        const int cp = (wid << 6) + lane;        // column pair index
        if (cp < (SP >> 1)) {
            float2* S2 = (float2*)S;
            const int rs = SP >> 1;              // row stride in float2
            float rx = 0.0f, ry = 0.0f;
            int a = 1;
            for (; a + 3 <= L; a += 4) {
                float2 v0 = S2[(a    ) * rs + cp];
                float2 v1 = S2[(a + 1) * rs + cp];
                float2 v2 = S2[(a + 2) * rs + cp];
                float2 v3 = S2[(a + 3) * rs + cp];
                rx += v0.x; ry += v0.y; S2[(a    ) * rs + cp] = make_float2(rx, ry);
                rx += v1.x; ry += v1.y; S2[(a + 1) * rs + cp] = make_float2(rx, ry);
                rx += v2.x; ry += v2.y; S2[(a + 2) * rs + cp] = make_float2(rx, ry);
                rx += v3.x; ry += v3.y; S2[(a + 3) * rs + cp] = make_float2(rx, ry);
            }
            for (; a <= L; ++a) {
                float2 v = S2[a * rs + cp];
                rx += v.x; ry += v.y;
                S2[a * rs + cp] = make_float2(rx, ry);
            }
        }
    }
    __syncthreads();

    // ---- write table to global (coalesced float2) ----
    {
        float2* Cg2 = (float2*)Cg;
        float2* S2  = (float2*)S;
        const int tot2 = (W * SP) >> 1;
        for (int k = tid; k < tot2; k += blockDim.x) Cg2[k] = S2[k];
    }
}

__global__ __launch_bounds__(256) void hyst_main(
    const float* __restrict__ h,
    const float* __restrict__ mesh,
    const float* __restrict__ Cg,
    const float* __restrict__ statg,
    const float* __restrict__ scale,
    const float* __restrict__ offset,
    float* __restrict__ out,
    int T, int L, int n)
{
    extern __shared__ float sm[];
    const int W  = L + 1;
    const int SP = (W + 1) & ~1;
    const int nc = (T + 63) >> 6;

    float* lh = sm;          // T floats
    float* us = sm + T;      // nc
    float* dsm = us + nc;    // nc

    const int tid  = threadIdx.x;
    const int lane = tid & 63;
    const int wid  = tid >> 6;
    const int nwv  = blockDim.x >> 6;

    // stage h[0..tmax] + chunk stats into LDS
    const int tmax = min(T - 1, (int)(blockIdx.x + 1) * nwv - 1);
    const int nh4  = (tmax + 4) >> 2;           // float4 count covering tmax
    const float4* h4 = (const float4*)h;
    float4* lh4 = (float4*)lh;
    for (int k = tid; k < nh4; k += blockDim.x) lh4[k] = h4[k];
    const int ncb = (tmax >> 6) + 1;
    for (int k = tid; k < ncb; k += blockDim.x) {
        us[k] = statg[k]; dsm[k] = statg[nc + k];
    }

    // xs levels: lane holds levels lane, +64, +128, +192
    float xsr[4];
#pragma unroll
    for (int k = 0; k < 4; ++k) {
        const int jj = lane + 64 * k;
        xsr[k] = (jj < L) ? mesh[2 * jj + 1] : 2.0f;  // 2.0 never matches
    }
    __syncthreads();

    const int t = blockIdx.x * nwv + wid;
    if (t >= T) return;

    float u_max = -1.0f, d_min = 2.0f;
    int Acov = 0, Bcov = L;
    int nrec = 0;                 // wave-uniform
    int r_up = 0, r_lo = 0, r_Ap = 0, r_Bp = 0;   // per-lane record slot
    float acc = 0.0f;             // per-lane deferred contributions

    auto flushrec = [&]() {
        if (lane < nrec) {
            float contrib;
            if (r_up) {
                contrib = Cg[r_lo * SP + r_Bp] - Cg[r_Ap * SP + r_Bp];
            } else {
                contrib = -((Cg[L * SP + r_Bp] - Cg[L * SP + r_lo])
                          - (Cg[r_Ap * SP + r_Bp] - Cg[r_Ap * SP + r_lo]));
            }
            acc += contrib;
        }
        nrec = 0;
    };
    auto count_le = [&](float v) -> int {
        return __popcll(__ballot(xsr[0] <= v)) + __popcll(__ballot(xsr[1] <= v))
             + __popcll(__ballot(xsr[2] <= v)) + __popcll(__ballot(xsr[3] <= v));
    };
    auto count_lt = [&](float v) -> int {
        return __popcll(__ballot(xsr[0] < v)) + __popcll(__ballot(xsr[1] < v))
             + __popcll(__ballot(xsr[2] < v)) + __popcll(__ballot(xsr[3] < v));
    };
    auto process_chunk = [&](int c) {
        const int i = (c << 6) + lane;      // i <= ct*64+63 <= T-1 here
        const float hv = lh[i];
        const float hp = (i > 0) ? lh[i - 1] : 0.0f;
        const bool valid = (i <= t);
        const bool isup = valid && (hv > hp);
        const bool isdn = valid && (hv < hp);
        unsigned long long mup = __ballot(isup && hv > u_max);
        unsigned long long mdn = __ballot(isdn && hv < d_min);
        unsigned long long m = mup | mdn;
        while (m) {
            const int rl = 63 - __builtin_clzll(m);   // largest i first
            const float v = __shfl(hv, rl);
            if ((mup >> rl) & 1ull) {
                u_max = v;
                const int lo = count_le(v);
                if (lo > Acov) {
                    if (lane == nrec) { r_up = 1; r_lo = lo; r_Ap = Acov; r_Bp = Bcov; }
                    ++nrec;
                    Acov = lo;
                    if (nrec == 64) flushrec();
                }
            } else {
                d_min = v;
                const int lo = count_lt(v);
                if (lo < Bcov) {
                    if (lane == nrec) { r_up = 0; r_lo = lo; r_Ap = Acov; r_Bp = Bcov; }
                    ++nrec;
                    Bcov = lo;
                    if (nrec == 64) flushrec();
                }
            }
            const unsigned long long below =
                (rl == 0) ? 0ull : ((1ull << rl) - 1ull);
            mup = __ballot(isup && hv > u_max) & below;
            mdn = __ballot(isdn && hv < d_min) & below;
            m = mup | mdn;
        }
    };

    const int ct = t >> 6;
    process_chunk(ct);  // partial top chunk (valid mask), exact

    for (int g = (ct - 1) >> 6; g >= 0; --g) {   // ct==0 -> skipped
        if (Acov >= L || Bcov <= 0) break;
        const int cbase = g << 6;
        const int c = cbase + lane;
        const bool act = (c < ct);
        const float vu = act ? us[c] : -1.0f;
        const float vd = act ? dsm[c] : 2.0f;
        // suffix scans (higher lanes = later chunks in backward order)
        float su = vu, sd = vd;
        for (int o = 1; o < 64; o <<= 1) {
            su = fmaxf(su, __shfl_down(su, o));
            sd = fminf(sd, __shfl_down(sd, o));
        }
        float sue = __shfl_down(su, 1);
        float sde = __shfl_down(sd, 1);
        if (lane == 63) { sue = -1.0f; sde = 2.0f; }
        const bool enter = act && ((vu > fmaxf(u_max, sue)) ||
                                   (vd < fminf(d_min, sde)));
        unsigned long long em = __ballot(enter);
        while (em) {
            const int rl = 63 - __builtin_clzll(em);
            process_chunk(cbase + rl);
            em &= ~(1ull << rl);
            if (Acov >= L || Bcov <= 0) break;
        }
    }

    flushrec();
    // leftover region keeps initial -1
    if (lane == 0) acc -= Cg[L * SP + Bcov] - Cg[Acov * SP + Bcov];
    for (int o = 1; o < 64; o <<= 1) acc += __shfl_xor(acc, o);
    if (lane == 0) out[t] = scale[0] * (acc / (float)n) + offset[0];
}

extern "C" void kernel_launch(void* const* d_in, const int* in_sizes, int n_in,
                              void* d_out, int out_size, void* d_ws, size_t ws_size,
                              hipStream_t stream) {
    const float* h      = (const float*)d_in[0];
    const float* mesh   = (const float*)d_in[1];
    const float* raw    = (const float*)d_in[2];
    const float* scale  = (const float*)d_in[3];
    const float* offset = (const float*)d_in[4];
    float* out = (float*)d_out;

    const int T = in_sizes[0];
    const int n = in_sizes[2];
    const int L = (int)((sqrt(8.0 * (double)n + 1.0) - 1.0) / 2.0 + 0.5);
    const int W = L + 1;
    const int SP = (W + 1) & ~1;
    const int nc = (T + 63) / 64;

    float* Cg    = (float*)d_ws;              // W*SP floats
    float* statg = Cg + (size_t)W * SP;       // 2*nc floats

    // K1: whole table + stats, one block
    const size_t shmem1 = (size_t)W * SP * sizeof(float);   // 162,408 B
    (void)hipFuncSetAttribute(reinterpret_cast<const void*>(build_all),
                              hipFuncAttributeMaxDynamicSharedMemorySize,
                              (int)shmem1);
    hipLaunchKernelGGL(build_all, dim3(1), dim3(1024), shmem1, stream,
                       h, raw, Cg, statg, T, L);

    // K2: main, wave per t, h + stats staged in LDS
    const int nwv = 4;                         // 256 threads = 4 waves
    const int grid = (T + nwv - 1) / nwv;      // 1024 blocks
    const size_t shmem2 = (size_t)(T + 2 * nc) * sizeof(float);  // ~16.9 KB
    hipLaunchKernelGGL(hyst_main, dim3(grid), dim3(256), shmem2, stream,
                       h, mesh, Cg, statg, scale, offset, out, T, L, n);
}